// Round 6
// baseline (9512.370 us; speedup 1.0000x reference)
//
#include <hip/hip_runtime.h>
#include <math.h>

#define HID    512
#define BATCH  512
#define TIN    512
#define TOUT   128
#define FOUR_H 2048
#define STEPS  (TIN + TOUT)

typedef __bf16 bf16x8 __attribute__((ext_vector_type(8)));
typedef float floatx4 __attribute__((ext_vector_type(4)));
typedef int   int4v   __attribute__((ext_vector_type(4)));

// R15: h exchange is WITHIN-XCD by construction (hang-proof census discovery),
// so h ops are sc0-only => served by the XCD's shared L2, not the LLC.
#define GLOADX4_L2(dst, p) \
    asm volatile("global_load_dwordx4 %0, %1, off sc0" : "=v"(dst) : "v"(p))
#define GSTOREX4_L2(p, v) \
    asm volatile("global_store_dwordx4 %0, %1, off sc0" :: "v"(p), "v"(v) : "memory")
// normal cached load -- for read-only streamed A (hits XCD L2 via L1 path)
#define GLOADX4_C(dst, p) \
    asm volatile("global_load_dwordx4 %0, %1, off" : "=v"(dst) : "v"(p))
// exact-count waits, tying the consumed registers
#define WAIT_T1(N, r) asm volatile("s_waitcnt vmcnt(" #N ")" : "+v"(r))
#define WAIT_T4(N, B) asm volatile("s_waitcnt vmcnt(" #N ")" \
    : "+v"((B)[0]), "+v"((B)[1]), "+v"((B)[2]), "+v"((B)[3]))

__device__ __forceinline__ float fsig(float x) {
    return __builtin_amdgcn_rcpf(1.0f + __expf(-x));
}
__device__ __forceinline__ float ftanh(float x) {
    return 1.0f - 2.0f * __builtin_amdgcn_rcpf(1.0f + __expf(2.0f * x));
}

// ---------- prep: pack Whh into blocked MFMA A-fragment order, bf16 hi/lo.
// m' = 4*j+g (row r = g*512+j); blk = m'>>7 (16 blocks x 128 rows),
// rg = (m'>>4)&7 (8 row-groups of 16), lr = m'&15; chunk = k>>5, lq=(k>>3)&3,
// lane = lq*16+lr.  elem-off = ((((blk*8+rg)*16+chunk)*2+pl)*512 + lane*8).
__global__ __launch_bounds__(256) void pack_w(
    const float* __restrict__ W, __bf16* __restrict__ Apk)
{
    int tid = blockIdx.x * 256 + threadIdx.x;   // 131072 threads
    int mp  = tid >> 6;                         // m' in [0,2048)
    int kg  = tid & 63;                         // k-group of 8
    int g   = mp & 3;
    int j   = mp >> 2;
    int r   = g * HID + j;
    int blk   = mp >> 7;
    int rg    = (mp >> 4) & 7;
    int lr    = mp & 15;
    int chunk = kg >> 2;
    int lq    = kg & 3;
    int lane  = lq * 16 + lr;
    const float* src = W + (size_t)r * HID + kg * 8;
    size_t offHi = ((size_t)(((blk * 8 + rg) * 16 + chunk) * 2 + 0) * 512) + lane * 8;
    size_t offLo = ((size_t)(((blk * 8 + rg) * 16 + chunk) * 2 + 1) * 512) + lane * 8;
    __bf16 hibuf[8], lobuf[8];
    #pragma unroll
    for (int i = 0; i < 8; ++i) {
        float x = src[i];
        __bf16 hi = (__bf16)x;
        hibuf[i] = hi;
        lobuf[i] = (__bf16)(x - (float)hi);
    }
    *(bf16x8*)(Apk + offHi) = *(bf16x8*)hibuf;
    *(bf16x8*)(Apk + offLo) = *(bf16x8*)lobuf;
}

__global__ __launch_bounds__(256) void pack_v(
    const float* __restrict__ Wih, const float* __restrict__ b,
    float* __restrict__ WihP, float* __restrict__ bP)
{
    int mp = blockIdx.x * 256 + threadIdx.x;
    int g  = mp & 3;
    int j  = mp >> 2;
    int r  = g * HID + j;
    WihP[mp] = Wih[r];
    bP[mp]   = b[r];
}

__global__ __launch_bounds__(256) void transpose_in(
    const float* __restrict__ in, float* __restrict__ outT)
{
    int idx = blockIdx.x * 256 + threadIdx.x;
    int t = idx >> 9, b = idx & 511;
    outT[idx] = in[(size_t)b * TIN + t];
}

// ---------- persistent cooperative kernel ----------
// grid 256 = 16 blk (128 m') x 16 by (32 b); block 256 = 4 waves; 1 block/CU
// (152KB LDS forces 1/CU; cooperative launch => all co-resident => exactly
// 32 blocks per XCD).
// R15: (by,blk) from census-based XCC discovery (bijective for ANY consistent
// xcc readings -- no slot collisions possible => no hang path). If XCC_ID is
// real, each group of 16 is same-XCD => h exchange sc0-only (XCD L2 coherent).
// Barrier stays DEVICE-scope (R10 proven): broken discovery => wrong results,
// never deadlock. Loop body + vmcnt tables byte-identical to R10 (4426 us).
__global__ __launch_bounds__(256, 1) void lstm_persistent(
    const __bf16* __restrict__ ApkEnc,   // [16 blk][8 rg][16 ch][2 pl][512], 4 MB
    const __bf16* __restrict__ ApkDec,
    const float* __restrict__ WihPenc, const float* __restrict__ biasPenc,
    const float* __restrict__ WihPdec, const float* __restrict__ biasPdec,
    const float* __restrict__ inputsT,
    const float* __restrict__ linW, const float* __restrict__ linb,
    __bf16* __restrict__ h0,         // [16 by][16 ch][256 piece][8] = 1 MB
    __bf16* __restrict__ h1,
    float* __restrict__ xacc,        // [3][BATCH] rotating decoder-feedback accum
    int* __restrict__ barrier_ws,    // arrive[0,512) phase[512,1024) census[1024,1032)
                                     // count[1032] slotc[1040,1048)
    float* __restrict__ out)         // [BATCH][TOUT]
{
    extern __shared__ char smem[];
    __bf16* Alds   = (__bf16*)smem;                    // 131072 B (A rows 0-63 hi/lo)
    char*   Bring  = smem + 131072;                    // 4 slots x 4096 B
    __bf16* hstage = (__bf16*)(smem + 147456);         // [64 rows][40] bf16 = 5120 B
    float*  xred   = (float*)(smem + 152576);          // [32]
    __shared__ int sh_gslot;

    const int tid  = threadIdx.x;
    const int lane = tid & 63;
    const int w    = tid >> 6;
    const int lr   = lane & 15;
    const int lq   = lane >> 4;

    // ---- hang-proof XCD discovery (one-time): census -> prefix -> slot ----
    if (tid == 0) {
        unsigned xcc = __builtin_amdgcn_s_getreg((31u << 11) | 20u) & 7u;  // HW_REG_XCC_ID
        __hip_atomic_fetch_add(&barrier_ws[1024 + (int)xcc], 1,
                               __ATOMIC_RELAXED, __HIP_MEMORY_SCOPE_AGENT);
        __hip_atomic_fetch_add(&barrier_ws[1032], 1,
                               __ATOMIC_RELEASE, __HIP_MEMORY_SCOPE_AGENT);
        while (__hip_atomic_load(&barrier_ws[1032],
                                 __ATOMIC_ACQUIRE, __HIP_MEMORY_SCOPE_AGENT) < 256)
            __builtin_amdgcn_s_sleep(2);
        int pre = 0;
        for (int x = 0; x < (int)xcc; ++x)
            pre += __hip_atomic_load(&barrier_ws[1024 + x],
                                     __ATOMIC_RELAXED, __HIP_MEMORY_SCOPE_AGENT);
        int slot = __hip_atomic_fetch_add(&barrier_ws[1040 + (int)xcc], 1,
                                          __ATOMIC_RELAXED, __HIP_MEMORY_SCOPE_AGENT);
        sh_gslot = pre + slot;   // bijection onto [0,256) for any census
    }
    __syncthreads();
    const int gslot = sh_gslot;
    const int by  = gslot >> 4;             // 16 batch groups (2 per XCD)
    const int blk = gslot & 15;             // 16 m' blocks within the group
    const int nbase = by * 32;
    const int rgbase = 2 * w;               // wave w owns row-groups {2w, 2w+1}
    const bool STREAM = (w >= 2);           // rg 4..7 streamed from L2

    // lane's packed-m' base for (mb): blk*128 + (rgbase+mb)*16 + lq*4
    const int m0a = blk * 128 + (rgbase + 0) * 16 + lq * 4;
    const int m0b = blk * 128 + (rgbase + 1) * 16 + lq * 4;
    const floatx4 wihE[2] = { *(const floatx4*)(WihPenc + m0a), *(const floatx4*)(WihPenc + m0b) };
    const floatx4 bE[2]   = { *(const floatx4*)(biasPenc + m0a), *(const floatx4*)(biasPenc + m0b) };
    const floatx4 wihD[2] = { *(const floatx4*)(WihPdec + m0a), *(const floatx4*)(WihPdec + m0b) };
    const floatx4 bD[2]   = { *(const floatx4*)(biasPdec + m0a), *(const floatx4*)(biasPdec + m0b) };
    const float lw[2] = { linW[m0a >> 2], linW[m0b >> 2] };   // j = m'>>2
    const float lb = linb[0];

    int bn[2];
    #pragma unroll
    for (int nt = 0; nt < 2; ++nt) bn[nt] = nbase + nt * 16 + lr;

    // zero hstage (step 0 reads own chunk of h(-1)=0 from it)
    {
        float* hz = (float*)hstage;
        for (int i = tid; i < 1280; i += 256) hz[i] = 0.f;
    }
    // stage resident A half (rg 0..3): linear 128 KB copy
    {
        const int4v* srcp = (const int4v*)(ApkEnc + (size_t)blk * 131072);
        int4v* dstp = (int4v*)Alds;
        for (int i = tid; i < 8192; i += 256) dstp[i] = srcp[i];
    }
    __syncthreads();

    float creg[2][2] = {{0.f, 0.f}, {0.f, 0.f}};

    int* arrive = barrier_ws + by * 32;
    int* phase  = barrier_ws + 512 + by * 32;

    for (int s = 0; s < STEPS; ++s) {
        const bool dec = (s >= TIN);
        const int  t   = s - TIN;
        const __bf16* Acur = dec ? ApkDec : ApkEnc;

        if (s == TIN) {
            const int4v* srcp = (const int4v*)(ApkDec + (size_t)blk * 131072);
            int4v* dstp = (int4v*)Alds;
            for (int i = tid; i < 8192; i += 256) dstp[i] = srcp[i];
            __syncthreads();
        }

        const __bf16* hin  = (s & 1) ? h1 : h0;
        __bf16*       hout = (s & 1) ? h0 : h1;
        const __bf16* srcB = hin + (size_t)by * 32768 + tid * 8;    // + chunk*2048
        const __bf16* Ag   = Acur + (size_t)blk * 131072;

        // ---- bookkeeping first (oldest vmem, drained by any later wait) ----
        float xq[2];
        if (dec) {
            if (tid < 32) xred[tid] = 0.f;
            if (blk == 0) {
                if (t >= 1 && tid < 32) {
                    float v = __hip_atomic_load(&xacc[((t - 1) % 3) * BATCH + nbase + tid],
                                                __ATOMIC_RELAXED, __HIP_MEMORY_SCOPE_AGENT) + lb;
                    out[(size_t)(nbase + tid) * TOUT + (t - 1)] = v;
                }
                if (tid >= 32 && tid < 64) {
                    __hip_atomic_store(&xacc[((t + 1) % 3) * BATCH + nbase + (tid - 32)], 0.0f,
                                       __ATOMIC_RELAXED, __HIP_MEMORY_SCOPE_AGENT);
                }
            }
            #pragma unroll
            for (int nt = 0; nt < 2; ++nt)
                xq[nt] = (t == 0) ? inputsT[(TIN - 1) * BATCH + bn[nt]]
                                  : __hip_atomic_load(&xacc[((t - 1) % 3) * BATCH + bn[nt]],
                                                      __ATOMIC_RELAXED, __HIP_MEMORY_SCOPE_AGENT) + lb;
        } else {
            #pragma unroll
            for (int nt = 0; nt < 2; ++nt)
                xq[nt] = inputsT[s * BATCH + bn[nt]];
        }
        asm volatile("" ::: "memory");   // pin bookkeeping vmem above staging asm

        // ---- prologue: chunk c(it)=(blk+it)&15; c(0)=blk comes from hstage.
        // Issue B1, B2 (L2) then A0 (cached, chunk blk). B3 issued at it0 (b').
        int4v st[4];
        int4v areg[2][4];
        GLOADX4_L2(st[1], srcB + (size_t)((blk + 1) & 15) * 2048);
        GLOADX4_L2(st[2], srcB + (size_t)((blk + 2) & 15) * 2048);
        if (STREAM) {
            #pragma unroll
            for (int mb = 0; mb < 2; ++mb)
                #pragma unroll
                for (int pl = 0; pl < 2; ++pl)
                    GLOADX4_C(areg[0][mb * 2 + pl],
                              Ag + (size_t)((((rgbase + mb) * 16 + blk) * 2 + pl) * 512) + lane * 8);
        }

        floatx4 acc[2][2];
        #pragma unroll
        for (int mb = 0; mb < 2; ++mb)
            #pragma unroll
            for (int nt = 0; nt < 2; ++nt) acc[mb][nt] = floatx4{0.f, 0.f, 0.f, 0.f};

        // ---- K-loop: 16 chunks, rotated. (a) wait+write B(it) [it>0];
        // (b') issue A(it+1), B(it+3); (c) sync [it>0]; (d) wait A(it), frags, 12 MFMAs.
        // vmcnt tables: R10-verified for this exact issue order.
        #pragma unroll
        for (int it = 0; it < 16; ++it) {
            const int c = (blk + it) & 15;

            if (it > 0) {
                // (a) wait B(it) resident, write ring slot
                if (STREAM) {
                    if      (it == 1 || it == 14) { WAIT_T1(5, st[it & 3]); }
                    else if (it <= 13)            { WAIT_T1(6, st[it & 3]); }
                    else                          { WAIT_T1(4, st[it & 3]); }
                } else {
                    if      (it <= 13) { WAIT_T1(2, st[it & 3]); }
                    else if (it == 14) { WAIT_T1(1, st[it & 3]); }
                    else               { WAIT_T1(0, st[it & 3]); }
                }
                *(int4v*)(Bring + (it & 3) * 4096 + tid * 16) = st[it & 3];
            }

            // (b') issue A(it+1) then B(it+3)
            if (STREAM && it + 1 < 16) {
                const int cn = (blk + it + 1) & 15;
                #pragma unroll
                for (int mb = 0; mb < 2; ++mb)
                    #pragma unroll
                    for (int pl = 0; pl < 2; ++pl)
                        GLOADX4_C(areg[(it + 1) & 1][mb * 2 + pl],
                                  Ag + (size_t)((((rgbase + mb) * 16 + cn) * 2 + pl) * 512) + lane * 8);
            }
            if (it + 3 < 16)
                GLOADX4_L2(st[(it + 3) & 3], srcB + (size_t)((blk + it + 3) & 15) * 2048);

            if (it > 0) __syncthreads();   // chunk `it` visible in ring

            // (d) A fragments
            bf16x8 ah[2], al[2];
            if (STREAM) {
                if      (it == 0)  { WAIT_T4(5, areg[0]); }
                else if (it <= 12) { WAIT_T4(6, areg[it & 1]); }
                else if (it == 13) { WAIT_T4(5, areg[1]); }
                else if (it == 14) { WAIT_T4(4, areg[0]); }
                else               { WAIT_T4(0, areg[1]); }
                #pragma unroll
                for (int mb = 0; mb < 2; ++mb) {
                    ah[mb] = __builtin_bit_cast(bf16x8, areg[it & 1][mb * 2 + 0]);
                    al[mb] = __builtin_bit_cast(bf16x8, areg[it & 1][mb * 2 + 1]);
                }
            } else {
                #pragma unroll
                for (int mb = 0; mb < 2; ++mb) {
                    const char* ap = (const char*)Alds
                        + (((rgbase + mb) * 16 + c) * 2) * 1024 + lane * 16;
                    ah[mb] = *(const bf16x8*)(ap);
                    al[mb] = *(const bf16x8*)(ap + 1024);
                }
            }

            // B fragments: it=0 straight from hstage (own tile), else from ring
            bf16x8 bh0, bl0, bh1, bl1;
            if (it == 0) {
                const char* hb = (const char*)hstage;
                const int kq = lane >> 4, lrp = lane & 15;
                bh0 = *(const bf16x8*)(hb + (     lrp) * 80 + kq * 16);
                bl0 = *(const bf16x8*)(hb + (32 + lrp) * 80 + kq * 16);
                bh1 = *(const bf16x8*)(hb + (16 + lrp) * 80 + kq * 16);
                bl1 = *(const bf16x8*)(hb + (48 + lrp) * 80 + kq * 16);
            } else {
                const char* bs = Bring + (it & 3) * 4096;
                bh0 = *(const bf16x8*)(bs + (0 * 128 + 0 * 64 + lane) * 16);
                bl0 = *(const bf16x8*)(bs + (0 * 128 + 1 * 64 + lane) * 16);
                bh1 = *(const bf16x8*)(bs + (1 * 128 + 0 * 64 + lane) * 16);
                bl1 = *(const bf16x8*)(bs + (1 * 128 + 1 * 64 + lane) * 16);
            }

            #pragma unroll
            for (int mb = 0; mb < 2; ++mb) {
                acc[mb][0] = __builtin_amdgcn_mfma_f32_16x16x32_bf16(ah[mb], bh0, acc[mb][0], 0, 0, 0);
                acc[mb][1] = __builtin_amdgcn_mfma_f32_16x16x32_bf16(ah[mb], bh1, acc[mb][1], 0, 0, 0);
                acc[mb][0] = __builtin_amdgcn_mfma_f32_16x16x32_bf16(al[mb], bh0, acc[mb][0], 0, 0, 0);
                acc[mb][1] = __builtin_amdgcn_mfma_f32_16x16x32_bf16(al[mb], bh1, acc[mb][1], 0, 0, 0);
                acc[mb][0] = __builtin_amdgcn_mfma_f32_16x16x32_bf16(ah[mb], bl0, acc[mb][0], 0, 0, 0);
                acc[mb][1] = __builtin_amdgcn_mfma_f32_16x16x32_bf16(ah[mb], bl1, acc[mb][1], 0, 0, 0);
            }
        }

        // ---- epilogue: gates, c in regs, stage h tile to LDS (40-elem rows) ----
        const floatx4* wih = dec ? wihD : wihE;
        const floatx4* bb  = dec ? bD   : bE;
        float px[2] = {0.f, 0.f};
        #pragma unroll
        for (int mb = 0; mb < 2; ++mb) {
            const int jlocal = (rgbase + mb) * 4 + lq;   // 0..31
            #pragma unroll
            for (int nt = 0; nt < 2; ++nt) {
                float x  = xq[nt];
                float i_ = fsig (acc[mb][nt][0] + bb[mb][0] + x * wih[mb][0]);
                float f_ = fsig (acc[mb][nt][1] + bb[mb][1] + x * wih[mb][1]);
                float g_ = ftanh(acc[mb][nt][2] + bb[mb][2] + x * wih[mb][2]);
                float o_ = fsig (acc[mb][nt][3] + bb[mb][3] + x * wih[mb][3]);
                float cv = f_ * creg[mb][nt] + i_ * g_;
                creg[mb][nt] = cv;
                float h  = o_ * ftanh(cv);
                __bf16 hh = (__bf16)h;
                int bl = nt * 16 + lr;
                hstage[bl * 40 + jlocal] = hh;                              // pl 0
                hstage[(32 + bl) * 40 + jlocal] = (__bf16)(h - (float)hh);  // pl 1
                if (dec) {
                    float v = h * lw[mb];
                    px[nt] += v;
                }
            }
        }
        if (dec) {
            #pragma unroll
            for (int nt = 0; nt < 2; ++nt) {
                px[nt] += __shfl_xor(px[nt], 16);
                px[nt] += __shfl_xor(px[nt], 32);   // sum over lq
            }
        }

        __syncthreads();   // hstage complete; xred zero visible

        // producer h store: thread tid -> piece tid of chunk `blk` (L2, same XCD)
        {
            int nt = tid >> 7, pl = (tid >> 6) & 1, ln = tid & 63;
            int kq = ln >> 4, lrp = ln & 15;
            const char* src = (const char*)hstage + (pl * 32 + nt * 16 + lrp) * 80 + kq * 16;
            int4v v = *(const int4v*)src;
            __bf16* dst = hout + (size_t)by * 32768 + blk * 2048 + tid * 8;
            GSTOREX4_L2(dst, v);
        }

        if (dec && lane < 16) {
            #pragma unroll
            for (int nt = 0; nt < 2; ++nt) atomicAdd(&xred[nt * 16 + lr], px[nt]);
        }
        __syncthreads();
        if (dec && tid < 32) {
            atomicAdd(&xacc[(t % 3) * BATCH + nbase + tid], xred[tid]);
        }

        // ---- group barrier: DEVICE-scope atomics (proven R10 mechanism) ----
        __builtin_amdgcn_s_waitcnt(0);   // h stores ack'd at L2; xacc atomics at LLC
        __syncthreads();
        if (tid == 0) {
            int n = __hip_atomic_fetch_add(arrive, 1, __ATOMIC_RELAXED, __HIP_MEMORY_SCOPE_AGENT);
            if (n == 16 * (s + 1) - 1) {
                __hip_atomic_store(phase, s + 1, __ATOMIC_RELAXED, __HIP_MEMORY_SCOPE_AGENT);
            } else {
                int p;
                do {
                    __builtin_amdgcn_s_sleep(2);
                    p = __hip_atomic_load(phase, __ATOMIC_RELAXED, __HIP_MEMORY_SCOPE_AGENT);
                } while (p < s + 1);
            }
        }
        __syncthreads();
    }

    // tail: out[:, TOUT-1]
    if (blk == 0 && tid < 32) {
        float v = __hip_atomic_load(&xacc[((TOUT - 1) % 3) * BATCH + nbase + tid],
                                    __ATOMIC_RELAXED, __HIP_MEMORY_SCOPE_AGENT) + lb;
        out[(size_t)(nbase + tid) * TOUT + (TOUT - 1)] = v;
    }
}

extern "C" void kernel_launch(void* const* d_in, const int* in_sizes, int n_in,
                              void* d_out, int out_size, void* d_ws, size_t ws_size,
                              hipStream_t stream) {
    const float* inputs  = (const float*)d_in[0];
    const float* enc_Wih = (const float*)d_in[2];
    const float* enc_Whh = (const float*)d_in[3];
    const float* enc_b   = (const float*)d_in[4];
    const float* dec_Wih = (const float*)d_in[5];
    const float* dec_Whh = (const float*)d_in[6];
    const float* dec_b   = (const float*)d_in[7];
    const float* lin_W   = (const float*)d_in[8];
    const float* lin_b   = (const float*)d_in[9];
    float* out = (float*)d_out;

    char* ws = (char*)d_ws;
    const size_t SZ_APK = (size_t)FOUR_H * HID * 2 * sizeof(__bf16);   // 4 MB
    const size_t SZ_V   = (size_t)FOUR_H * sizeof(float);
    const size_t SZ_HF  = (size_t)16 * 16 * 256 * 8 * sizeof(__bf16);  // 1 MB

    __bf16* ApkEnc = (__bf16*)(ws);
    __bf16* ApkDec = (__bf16*)(ws + SZ_APK);
    char* p = ws + 2 * SZ_APK;
    float* WihPenc  = (float*)p;  p += SZ_V;
    float* biasPenc = (float*)p;  p += SZ_V;
    float* WihPdec  = (float*)p;  p += SZ_V;
    float* biasPdec = (float*)p;  p += SZ_V;
    float* inputsT  = (float*)p;  p += (size_t)TIN * BATCH * sizeof(float);
    __bf16* h0 = (__bf16*)p;      p += SZ_HF;
    __bf16* h1 = (__bf16*)p;      p += SZ_HF;
    float* xacc  = (float*)p;     p += 3 * BATCH * sizeof(float);
    int* barrier_ws = (int*)p;    p += 1056 * sizeof(int);

    pack_w<<<512, 256, 0, stream>>>(enc_Whh, ApkEnc);
    pack_w<<<512, 256, 0, stream>>>(dec_Whh, ApkDec);
    pack_v<<<8, 256, 0, stream>>>(enc_Wih, enc_b, WihPenc, biasPenc);
    pack_v<<<8, 256, 0, stream>>>(dec_Wih, dec_b, WihPdec, biasPdec);
    transpose_in<<<1024, 256, 0, stream>>>(inputs, inputsT);
    hipMemsetAsync(h0, 0, SZ_HF, stream);
    hipMemsetAsync(xacc, 0, 3 * BATCH * sizeof(float), stream);
    hipMemsetAsync(barrier_ws, 0, 1056 * sizeof(int), stream);

    const int shmem = 131072 + 16384 + 5120 + 128;   // A + ring + hstage(padded) + xred
    hipFuncSetAttribute((const void*)lstm_persistent,
                        hipFuncAttributeMaxDynamicSharedMemorySize, shmem);

    void* args[] = {
        (void*)&ApkEnc, (void*)&ApkDec,
        (void*)&WihPenc, (void*)&biasPenc, (void*)&WihPdec, (void*)&biasPdec,
        (void*)&inputsT, (void*)&lin_W, (void*)&lin_b,
        (void*)&h0, (void*)&h1,
        (void*)&xacc, (void*)&barrier_ws, (void*)&out
    };
    hipLaunchCooperativeKernel((void*)lstm_persistent, dim3(256), dim3(256),
                               args, shmem, stream);
}

// Round 7
// 4200.346 us; speedup vs baseline: 2.2647x; 2.2647x over previous
//
#include <hip/hip_runtime.h>
#include <math.h>

#define HID    512
#define BATCH  512
#define TIN    512
#define TOUT   128
#define FOUR_H 2048
#define STEPS  (TIN + TOUT)

typedef __bf16 bf16x8 __attribute__((ext_vector_type(8)));
typedef float floatx4 __attribute__((ext_vector_type(4)));
typedef int   int4v   __attribute__((ext_vector_type(4)));

// LLC-direct (bypass L1+L2) -- for h exchange (coherence point = Infinity Cache).
// R15 measured: sc0-only (L2) path is ~2x SLOWER per-CU; sc0sc1 is the fast path.
#define GLOADX4_SC(dst, p) \
    asm volatile("global_load_dwordx4 %0, %1, off sc0 sc1" : "=v"(dst) : "v"(p))
#define GSTOREX4_SC(p, v) \
    asm volatile("global_store_dwordx4 %0, %1, off sc0 sc1" :: "v"(p), "v"(v) : "memory")
// normal cached load -- for read-only streamed A (hits XCD L2)
#define GLOADX4_C(dst, p) \
    asm volatile("global_load_dwordx4 %0, %1, off" : "=v"(dst) : "v"(p))
// exact-count waits, tying the consumed registers
#define WAIT_T1(N, r) asm volatile("s_waitcnt vmcnt(" #N ")" : "+v"(r))
#define WAIT_T4(N, B) asm volatile("s_waitcnt vmcnt(" #N ")" \
    : "+v"((B)[0]), "+v"((B)[1]), "+v"((B)[2]), "+v"((B)[3]))

__device__ __forceinline__ float fsig(float x) {
    return __builtin_amdgcn_rcpf(1.0f + __expf(-x));
}
__device__ __forceinline__ float ftanh(float x) {
    return 1.0f - 2.0f * __builtin_amdgcn_rcpf(1.0f + __expf(2.0f * x));
}

// ---------- prep: pack Whh into blocked MFMA A-fragment order, bf16 hi/lo.
// m' = 4*j+g (row r = g*512+j); blk = m'>>7 (16 blocks x 128 rows),
// rg = (m'>>4)&7 (8 row-groups of 16), lr = m'&15; chunk = k>>5, lq=(k>>3)&3,
// lane = lq*16+lr.  elem-off = ((((blk*8+rg)*16+chunk)*2+pl)*512 + lane*8).
__global__ __launch_bounds__(256) void pack_w(
    const float* __restrict__ W, __bf16* __restrict__ Apk)
{
    int tid = blockIdx.x * 256 + threadIdx.x;   // 131072 threads
    int mp  = tid >> 6;                         // m' in [0,2048)
    int kg  = tid & 63;                         // k-group of 8
    int g   = mp & 3;
    int j   = mp >> 2;
    int r   = g * HID + j;
    int blk   = mp >> 7;
    int rg    = (mp >> 4) & 7;
    int lr    = mp & 15;
    int chunk = kg >> 2;
    int lq    = kg & 3;
    int lane  = lq * 16 + lr;
    const float* src = W + (size_t)r * HID + kg * 8;
    size_t offHi = ((size_t)(((blk * 8 + rg) * 16 + chunk) * 2 + 0) * 512) + lane * 8;
    size_t offLo = ((size_t)(((blk * 8 + rg) * 16 + chunk) * 2 + 1) * 512) + lane * 8;
    __bf16 hibuf[8], lobuf[8];
    #pragma unroll
    for (int i = 0; i < 8; ++i) {
        float x = src[i];
        __bf16 hi = (__bf16)x;
        hibuf[i] = hi;
        lobuf[i] = (__bf16)(x - (float)hi);
    }
    *(bf16x8*)(Apk + offHi) = *(bf16x8*)hibuf;
    *(bf16x8*)(Apk + offLo) = *(bf16x8*)lobuf;
}

__global__ __launch_bounds__(256) void pack_v(
    const float* __restrict__ Wih, const float* __restrict__ b,
    float* __restrict__ WihP, float* __restrict__ bP)
{
    int mp = blockIdx.x * 256 + threadIdx.x;
    int g  = mp & 3;
    int j  = mp >> 2;
    int r  = g * HID + j;
    WihP[mp] = Wih[r];
    bP[mp]   = b[r];
}

__global__ __launch_bounds__(256) void transpose_in(
    const float* __restrict__ in, float* __restrict__ outT)
{
    int idx = blockIdx.x * 256 + threadIdx.x;
    int t = idx >> 9, b = idx & 511;
    outT[idx] = in[(size_t)b * TIN + t];
}

// ---------- persistent cooperative kernel ----------
// grid 256 = 16 blk (128 m') x 16 by (32 b); block 256 = 4 waves; 1 block/CU.
// R10 loop (best measured, 4426) + R16 barrier overlap:
//   publish: waitcnt(0) -> sync -> tid0 FIRE-AND-FORGET fetch_add(arrive)
//   overlap window: A0/A1 prefetch + it0(next step, own chunk from hstage)
//                   [+ dec Alds restage at s+1==TIN] run DURING the barrier wait
//   gate: tid0 polls count >= 16(s+1) (no phase cell, no last-arriver hop), sync.
// Count monotone, every block adds before polling => no circular wait.
// vmcnt tables re-derived for the shifted schedule (A0/A1 pre-barrier,
// B1,B2,B3 at step top; age-order simulated it-by-it, see R16 notes).
__global__ __launch_bounds__(256, 1) void lstm_persistent(
    const __bf16* __restrict__ ApkEnc,   // [16 blk][8 rg][16 ch][2 pl][512], 4 MB
    const __bf16* __restrict__ ApkDec,
    const float* __restrict__ WihPenc, const float* __restrict__ biasPenc,
    const float* __restrict__ WihPdec, const float* __restrict__ biasPdec,
    const float* __restrict__ inputsT,
    const float* __restrict__ linW, const float* __restrict__ linb,
    __bf16* __restrict__ h0,         // [16 by][16 ch][256 piece][8] = 1 MB
    __bf16* __restrict__ h1,
    float* __restrict__ xacc,        // [3][BATCH] rotating decoder-feedback accum
    int* __restrict__ barrier_ws,    // arrive counters [by*32]
    float* __restrict__ out)         // [BATCH][TOUT]
{
    extern __shared__ char smem[];
    __bf16* Alds   = (__bf16*)smem;                    // 131072 B (A rows 0-63 hi/lo)
    char*   Bring  = smem + 131072;                    // 4 slots x 4096 B
    __bf16* hstage = (__bf16*)(smem + 147456);         // [64 rows][40] bf16 = 5120 B
    float*  xred   = (float*)(smem + 152576);          // [32]

    const int tid  = threadIdx.x;
    const int lane = tid & 63;
    const int w    = tid >> 6;
    const int lr   = lane & 15;
    const int lq   = lane >> 4;
    const int by   = blockIdx.x >> 4;       // 16 batch groups
    const int blk  = blockIdx.x & 15;       // 16 m' blocks
    const int nbase = by * 32;
    const int rgbase = 2 * w;               // wave w owns row-groups {2w, 2w+1}
    const bool STREAM = (w >= 2);           // rg 4..7 streamed from L2

    int* arrive = barrier_ws + by * 32;

    // lane's packed-m' base for (mb): blk*128 + (rgbase+mb)*16 + lq*4
    const int m0a = blk * 128 + (rgbase + 0) * 16 + lq * 4;
    const int m0b = blk * 128 + (rgbase + 1) * 16 + lq * 4;
    const floatx4 wihE[2] = { *(const floatx4*)(WihPenc + m0a), *(const floatx4*)(WihPenc + m0b) };
    const floatx4 bE[2]   = { *(const floatx4*)(biasPenc + m0a), *(const floatx4*)(biasPenc + m0b) };
    const floatx4 wihD[2] = { *(const floatx4*)(WihPdec + m0a), *(const floatx4*)(WihPdec + m0b) };
    const floatx4 bD[2]   = { *(const floatx4*)(biasPdec + m0a), *(const floatx4*)(biasPdec + m0b) };
    const float lw[2] = { linW[m0a >> 2], linW[m0b >> 2] };   // j = m'>>2
    const float lb = linb[0];

    int bn[2];
    #pragma unroll
    for (int nt = 0; nt < 2; ++nt) bn[nt] = nbase + nt * 16 + lr;

    // zero hstage (step 0's it0 reads own chunk of h(-1)=0 from it)
    {
        float* hz = (float*)hstage;
        for (int i = tid; i < 1280; i += 256) hz[i] = 0.f;
    }
    // stage resident A half (rg 0..3): linear 128 KB copy
    {
        const int4v* srcp = (const int4v*)(ApkEnc + (size_t)blk * 131072);
        int4v* dstp = (int4v*)Alds;
        for (int i = tid; i < 8192; i += 256) dstp[i] = srcp[i];
    }
    __syncthreads();
    __builtin_amdgcn_s_waitcnt(0);   // clean vmcnt state before scheduled issues

    float creg[2][2] = {{0.f, 0.f}, {0.f, 0.f}};

    floatx4 acc[2][2];
    int4v areg[2][4];

    // ---- pre-segment for step 0: A0/A1 prefetch + it0 (hstage = 0 -> acc = 0) ----
    {
        const __bf16* AgN = ApkEnc + (size_t)blk * 131072;
        #pragma unroll
        for (int mb = 0; mb < 2; ++mb)
            #pragma unroll
            for (int nt = 0; nt < 2; ++nt) acc[mb][nt] = floatx4{0.f, 0.f, 0.f, 0.f};
        if (STREAM) {
            #pragma unroll
            for (int mb = 0; mb < 2; ++mb)
                #pragma unroll
                for (int pl = 0; pl < 2; ++pl)
                    GLOADX4_C(areg[0][mb * 2 + pl],
                              AgN + (size_t)((((rgbase + mb) * 16 + blk) * 2 + pl) * 512) + lane * 8);
            #pragma unroll
            for (int mb = 0; mb < 2; ++mb)
                #pragma unroll
                for (int pl = 0; pl < 2; ++pl)
                    GLOADX4_C(areg[1][mb * 2 + pl],
                              AgN + (size_t)((((rgbase + mb) * 16 + ((blk + 1) & 15)) * 2 + pl) * 512) + lane * 8);
            WAIT_T4(4, areg[0]);
        }
        // it0 for step 0
        bf16x8 ah[2], al[2];
        if (STREAM) {
            #pragma unroll
            for (int mb = 0; mb < 2; ++mb) {
                ah[mb] = __builtin_bit_cast(bf16x8, areg[0][mb * 2 + 0]);
                al[mb] = __builtin_bit_cast(bf16x8, areg[0][mb * 2 + 1]);
            }
        } else {
            #pragma unroll
            for (int mb = 0; mb < 2; ++mb) {
                const char* ap = (const char*)Alds + (((rgbase + mb) * 16 + blk) * 2) * 1024 + lane * 16;
                ah[mb] = *(const bf16x8*)(ap);
                al[mb] = *(const bf16x8*)(ap + 1024);
            }
        }
        const char* hb = (const char*)hstage;
        const int kq = lane >> 4, lrp = lane & 15;
        bf16x8 bh0 = *(const bf16x8*)(hb + (     lrp) * 80 + kq * 16);
        bf16x8 bl0 = *(const bf16x8*)(hb + (32 + lrp) * 80 + kq * 16);
        bf16x8 bh1 = *(const bf16x8*)(hb + (16 + lrp) * 80 + kq * 16);
        bf16x8 bl1 = *(const bf16x8*)(hb + (48 + lrp) * 80 + kq * 16);
        #pragma unroll
        for (int mb = 0; mb < 2; ++mb) {
            acc[mb][0] = __builtin_amdgcn_mfma_f32_16x16x32_bf16(ah[mb], bh0, acc[mb][0], 0, 0, 0);
            acc[mb][1] = __builtin_amdgcn_mfma_f32_16x16x32_bf16(ah[mb], bh1, acc[mb][1], 0, 0, 0);
            acc[mb][0] = __builtin_amdgcn_mfma_f32_16x16x32_bf16(al[mb], bh0, acc[mb][0], 0, 0, 0);
            acc[mb][1] = __builtin_amdgcn_mfma_f32_16x16x32_bf16(al[mb], bh1, acc[mb][1], 0, 0, 0);
            acc[mb][0] = __builtin_amdgcn_mfma_f32_16x16x32_bf16(ah[mb], bl0, acc[mb][0], 0, 0, 0);
            acc[mb][1] = __builtin_amdgcn_mfma_f32_16x16x32_bf16(ah[mb], bl1, acc[mb][1], 0, 0, 0);
        }
    }

    for (int s = 0; s < STEPS; ++s) {
        const bool dec = (s >= TIN);
        const int  t   = s - TIN;
        const __bf16* Acur = dec ? ApkDec : ApkEnc;

        const __bf16* hin  = (s & 1) ? h1 : h0;
        __bf16*       hout = (s & 1) ? h0 : h1;
        const __bf16* srcB = hin + (size_t)by * 32768 + tid * 8;    // + chunk*2048
        const __bf16* Ag   = Acur + (size_t)blk * 131072;

        // ---- bookkeeping first (oldest vmem, drained by it1's wait) ----
        float xq[2];
        if (dec) {
            if (tid < 32) xred[tid] = 0.f;
            if (blk == 0) {
                if (t >= 1 && tid < 32) {
                    float v = __hip_atomic_load(&xacc[((t - 1) % 3) * BATCH + nbase + tid],
                                                __ATOMIC_RELAXED, __HIP_MEMORY_SCOPE_AGENT) + lb;
                    out[(size_t)(nbase + tid) * TOUT + (t - 1)] = v;
                }
                if (tid >= 32 && tid < 64) {
                    __hip_atomic_store(&xacc[((t + 1) % 3) * BATCH + nbase + (tid - 32)], 0.0f,
                                       __ATOMIC_RELAXED, __HIP_MEMORY_SCOPE_AGENT);
                }
            }
            #pragma unroll
            for (int nt = 0; nt < 2; ++nt)
                xq[nt] = (t == 0) ? inputsT[(TIN - 1) * BATCH + bn[nt]]
                                  : __hip_atomic_load(&xacc[((t - 1) % 3) * BATCH + bn[nt]],
                                                      __ATOMIC_RELAXED, __HIP_MEMORY_SCOPE_AGENT) + lb;
        } else {
            #pragma unroll
            for (int nt = 0; nt < 2; ++nt)
                xq[nt] = inputsT[s * BATCH + bn[nt]];
        }
        asm volatile("" ::: "memory");   // pin bookkeeping vmem above staging asm

        // ---- B prologue: chunks blk+1, blk+2, blk+3 (it0 already done pre-barrier) ----
        int4v st[4];
        GLOADX4_SC(st[1], srcB + (size_t)((blk + 1) & 15) * 2048);
        GLOADX4_SC(st[2], srcB + (size_t)((blk + 2) & 15) * 2048);
        GLOADX4_SC(st[3], srcB + (size_t)((blk + 3) & 15) * 2048);

        // ---- K-loop it=1..15. STREAM age order:
        // [A1(pre-seg) | bk | B1,B2,B3 | it1:(A2,B4) it2:(A3,B5) ... it12:(A13,B15)
        //  it13:(A14) it14:(A15)]
        // (a): it1=2 (forces A1,bk,B1), it2=6, it3..15 none (prior (d) retired B(it)).
        // (d): it1 none (A1 retired at it1(a)), it2-12=6, it13=5, it14=4, it15=0.
        // non-STREAM (a): <=13 -> 2, 14 -> 1, 15 -> 0 (R10 table).
        #pragma unroll
        for (int it = 1; it < 16; ++it) {
            const int c = (blk + it) & 15;

            // (a) wait B(it) resident, write ring slot
            if (STREAM) {
                if      (it == 1) { WAIT_T1(2, st[1]); }
                else if (it == 2) { WAIT_T1(6, st[2]); }
                // it >= 3: B(it) already forced by it-1's (d) wait
            } else {
                if      (it <= 13) { WAIT_T1(2, st[it & 3]); }
                else if (it == 14) { WAIT_T1(1, st[it & 3]); }
                else               { WAIT_T1(0, st[it & 3]); }
            }
            *(int4v*)(Bring + (it & 3) * 4096 + tid * 16) = st[it & 3];

            // (b') issue A(it+1) then B(it+3)
            if (STREAM && it + 1 < 16) {
                const int cn = (blk + it + 1) & 15;
                #pragma unroll
                for (int mb = 0; mb < 2; ++mb)
                    #pragma unroll
                    for (int pl = 0; pl < 2; ++pl)
                        GLOADX4_C(areg[(it + 1) & 1][mb * 2 + pl],
                                  Ag + (size_t)((((rgbase + mb) * 16 + cn) * 2 + pl) * 512) + lane * 8);
            }
            if (it + 3 < 16)
                GLOADX4_SC(st[(it + 3) & 3], srcB + (size_t)((blk + it + 3) & 15) * 2048);

            __syncthreads();   // chunk `it` visible in ring

            // (d) A fragments
            bf16x8 ah[2], al[2];
            if (STREAM) {
                if      (it == 1)  { /* A1 retired at (a) */ }
                else if (it <= 12) { WAIT_T4(6, areg[it & 1]); }
                else if (it == 13) { WAIT_T4(5, areg[1]); }
                else if (it == 14) { WAIT_T4(4, areg[0]); }
                else               { WAIT_T4(0, areg[1]); }
                #pragma unroll
                for (int mb = 0; mb < 2; ++mb) {
                    ah[mb] = __builtin_bit_cast(bf16x8, areg[it & 1][mb * 2 + 0]);
                    al[mb] = __builtin_bit_cast(bf16x8, areg[it & 1][mb * 2 + 1]);
                }
            } else {
                #pragma unroll
                for (int mb = 0; mb < 2; ++mb) {
                    const char* ap = (const char*)Alds
                        + (((rgbase + mb) * 16 + c) * 2) * 1024 + lane * 16;
                    ah[mb] = *(const bf16x8*)(ap);
                    al[mb] = *(const bf16x8*)(ap + 1024);
                }
            }

            const char* bs = Bring + (it & 3) * 4096;
            bf16x8 bh0 = *(const bf16x8*)(bs + (0 * 128 + 0 * 64 + lane) * 16);
            bf16x8 bl0 = *(const bf16x8*)(bs + (0 * 128 + 1 * 64 + lane) * 16);
            bf16x8 bh1 = *(const bf16x8*)(bs + (1 * 128 + 0 * 64 + lane) * 16);
            bf16x8 bl1 = *(const bf16x8*)(bs + (1 * 128 + 1 * 64 + lane) * 16);

            #pragma unroll
            for (int mb = 0; mb < 2; ++mb) {
                acc[mb][0] = __builtin_amdgcn_mfma_f32_16x16x32_bf16(ah[mb], bh0, acc[mb][0], 0, 0, 0);
                acc[mb][1] = __builtin_amdgcn_mfma_f32_16x16x32_bf16(ah[mb], bh1, acc[mb][1], 0, 0, 0);
                acc[mb][0] = __builtin_amdgcn_mfma_f32_16x16x32_bf16(al[mb], bh0, acc[mb][0], 0, 0, 0);
                acc[mb][1] = __builtin_amdgcn_mfma_f32_16x16x32_bf16(al[mb], bh1, acc[mb][1], 0, 0, 0);
                acc[mb][0] = __builtin_amdgcn_mfma_f32_16x16x32_bf16(ah[mb], bl0, acc[mb][0], 0, 0, 0);
                acc[mb][1] = __builtin_amdgcn_mfma_f32_16x16x32_bf16(ah[mb], bl1, acc[mb][1], 0, 0, 0);
            }
        }

        // ---- epilogue: gates, c in regs, stage h tile to LDS (40-elem rows) ----
        const floatx4* wih = dec ? wihD : wihE;
        const floatx4* bb  = dec ? bD   : bE;
        float px[2] = {0.f, 0.f};
        #pragma unroll
        for (int mb = 0; mb < 2; ++mb) {
            const int jlocal = (rgbase + mb) * 4 + lq;   // 0..31
            #pragma unroll
            for (int nt = 0; nt < 2; ++nt) {
                float x  = xq[nt];
                float i_ = fsig (acc[mb][nt][0] + bb[mb][0] + x * wih[mb][0]);
                float f_ = fsig (acc[mb][nt][1] + bb[mb][1] + x * wih[mb][1]);
                float g_ = ftanh(acc[mb][nt][2] + bb[mb][2] + x * wih[mb][2]);
                float o_ = fsig (acc[mb][nt][3] + bb[mb][3] + x * wih[mb][3]);
                float cv = f_ * creg[mb][nt] + i_ * g_;
                creg[mb][nt] = cv;
                float h  = o_ * ftanh(cv);
                __bf16 hh = (__bf16)h;
                int bl = nt * 16 + lr;
                hstage[bl * 40 + jlocal] = hh;                              // pl 0
                hstage[(32 + bl) * 40 + jlocal] = (__bf16)(h - (float)hh);  // pl 1
                if (dec) {
                    float v = h * lw[mb];
                    px[nt] += v;
                }
            }
        }
        if (dec) {
            #pragma unroll
            for (int nt = 0; nt < 2; ++nt) {
                px[nt] += __shfl_xor(px[nt], 16);
                px[nt] += __shfl_xor(px[nt], 32);   // sum over lq
            }
        }

        __syncthreads();   // hstage complete; xred zero visible

        // producer h store: thread tid -> piece tid of chunk `blk` (coalesced sc1)
        {
            int nt = tid >> 7, pl = (tid >> 6) & 1, ln = tid & 63;
            int kq = ln >> 4, lrp = ln & 15;
            const char* src = (const char*)hstage + (pl * 32 + nt * 16 + lrp) * 80 + kq * 16;
            int4v v = *(const int4v*)src;
            __bf16* dst = hout + (size_t)by * 32768 + blk * 2048 + tid * 8;
            GSTOREX4_SC(dst, v);
        }

        if (dec && lane < 16) {
            #pragma unroll
            for (int nt = 0; nt < 2; ++nt) atomicAdd(&xred[nt * 16 + lr], px[nt]);
        }
        __syncthreads();
        if (dec && tid < 32) {
            atomicAdd(&xacc[(t % 3) * BATCH + nbase + tid], xred[tid]);
        }

        // ---- publish: drain (release; own sc reads retired), FIRE arrive ----
        __builtin_amdgcn_s_waitcnt(0);   // h stores + xacc atomics at LLC
        __syncthreads();
        if (tid == 0) {
            (void)__hip_atomic_fetch_add(arrive, 1, __ATOMIC_RELAXED, __HIP_MEMORY_SCOPE_AGENT);
        }

        // ---- overlap window: restage / A-prefetch / it0(s+1) during barrier wait ----
        if (s + 1 == TIN) {
            const int4v* srcp = (const int4v*)(ApkDec + (size_t)blk * 131072);
            int4v* dstp = (int4v*)Alds;
            for (int i = tid; i < 8192; i += 256) dstp[i] = srcp[i];
            __syncthreads();
            __builtin_amdgcn_s_waitcnt(0);   // clean vmcnt before scheduled A issues
        }
        if (s + 1 < STEPS) {
            const __bf16* AgN = ((s + 1 >= TIN) ? ApkDec : ApkEnc) + (size_t)blk * 131072;
            #pragma unroll
            for (int mb = 0; mb < 2; ++mb)
                #pragma unroll
                for (int nt = 0; nt < 2; ++nt) acc[mb][nt] = floatx4{0.f, 0.f, 0.f, 0.f};
            if (STREAM) {
                #pragma unroll
                for (int mb = 0; mb < 2; ++mb)
                    #pragma unroll
                    for (int pl = 0; pl < 2; ++pl)
                        GLOADX4_C(areg[0][mb * 2 + pl],
                                  AgN + (size_t)((((rgbase + mb) * 16 + blk) * 2 + pl) * 512) + lane * 8);
                #pragma unroll
                for (int mb = 0; mb < 2; ++mb)
                    #pragma unroll
                    for (int pl = 0; pl < 2; ++pl)
                        GLOADX4_C(areg[1][mb * 2 + pl],
                                  AgN + (size_t)((((rgbase + mb) * 16 + ((blk + 1) & 15)) * 2 + pl) * 512) + lane * 8);
                WAIT_T4(4, areg[0]);
            }
            // it0 for step s+1: B from hstage (own tile), A chunk blk
            bf16x8 ah[2], al[2];
            if (STREAM) {
                #pragma unroll
                for (int mb = 0; mb < 2; ++mb) {
                    ah[mb] = __builtin_bit_cast(bf16x8, areg[0][mb * 2 + 0]);
                    al[mb] = __builtin_bit_cast(bf16x8, areg[0][mb * 2 + 1]);
                }
            } else {
                #pragma unroll
                for (int mb = 0; mb < 2; ++mb) {
                    const char* ap = (const char*)Alds + (((rgbase + mb) * 16 + blk) * 2) * 1024 + lane * 16;
                    ah[mb] = *(const bf16x8*)(ap);
                    al[mb] = *(const bf16x8*)(ap + 1024);
                }
            }
            const char* hb = (const char*)hstage;
            const int kq = lane >> 4, lrp = lane & 15;
            bf16x8 bh0 = *(const bf16x8*)(hb + (     lrp) * 80 + kq * 16);
            bf16x8 bl0 = *(const bf16x8*)(hb + (32 + lrp) * 80 + kq * 16);
            bf16x8 bh1 = *(const bf16x8*)(hb + (16 + lrp) * 80 + kq * 16);
            bf16x8 bl1 = *(const bf16x8*)(hb + (48 + lrp) * 80 + kq * 16);
            #pragma unroll
            for (int mb = 0; mb < 2; ++mb) {
                acc[mb][0] = __builtin_amdgcn_mfma_f32_16x16x32_bf16(ah[mb], bh0, acc[mb][0], 0, 0, 0);
                acc[mb][1] = __builtin_amdgcn_mfma_f32_16x16x32_bf16(ah[mb], bh1, acc[mb][1], 0, 0, 0);
                acc[mb][0] = __builtin_amdgcn_mfma_f32_16x16x32_bf16(al[mb], bh0, acc[mb][0], 0, 0, 0);
                acc[mb][1] = __builtin_amdgcn_mfma_f32_16x16x32_bf16(al[mb], bh1, acc[mb][1], 0, 0, 0);
                acc[mb][0] = __builtin_amdgcn_mfma_f32_16x16x32_bf16(ah[mb], bl0, acc[mb][0], 0, 0, 0);
                acc[mb][1] = __builtin_amdgcn_mfma_f32_16x16x32_bf16(ah[mb], bl1, acc[mb][1], 0, 0, 0);
            }
        }

        // ---- gate: poll count (first poll typically lands after all 16 adds) ----
        if (tid == 0) {
            int target = 16 * (s + 1);
            int n;
            do {
                n = __hip_atomic_load(arrive, __ATOMIC_RELAXED, __HIP_MEMORY_SCOPE_AGENT);
                if (n >= target) break;
                __builtin_amdgcn_s_sleep(2);
            } while (1);
        }
        __syncthreads();
    }

    // tail: out[:, TOUT-1]  (last poll guaranteed all blocks' final xacc drained)
    if (blk == 0 && tid < 32) {
        float v = __hip_atomic_load(&xacc[((TOUT - 1) % 3) * BATCH + nbase + tid],
                                    __ATOMIC_RELAXED, __HIP_MEMORY_SCOPE_AGENT) + lb;
        out[(size_t)(nbase + tid) * TOUT + (TOUT - 1)] = v;
    }
}

extern "C" void kernel_launch(void* const* d_in, const int* in_sizes, int n_in,
                              void* d_out, int out_size, void* d_ws, size_t ws_size,
                              hipStream_t stream) {
    const float* inputs  = (const float*)d_in[0];
    const float* enc_Wih = (const float*)d_in[2];
    const float* enc_Whh = (const float*)d_in[3];
    const float* enc_b   = (const float*)d_in[4];
    const float* dec_Wih = (const float*)d_in[5];
    const float* dec_Whh = (const float*)d_in[6];
    const float* dec_b   = (const float*)d_in[7];
    const float* lin_W   = (const float*)d_in[8];
    const float* lin_b   = (const float*)d_in[9];
    float* out = (float*)d_out;

    char* ws = (char*)d_ws;
    const size_t SZ_APK = (size_t)FOUR_H * HID * 2 * sizeof(__bf16);   // 4 MB
    const size_t SZ_V   = (size_t)FOUR_H * sizeof(float);
    const size_t SZ_HF  = (size_t)16 * 16 * 256 * 8 * sizeof(__bf16);  // 1 MB

    __bf16* ApkEnc = (__bf16*)(ws);
    __bf16* ApkDec = (__bf16*)(ws + SZ_APK);
    char* p = ws + 2 * SZ_APK;
    float* WihPenc  = (float*)p;  p += SZ_V;
    float* biasPenc = (float*)p;  p += SZ_V;
    float* WihPdec  = (float*)p;  p += SZ_V;
    float* biasPdec = (float*)p;  p += SZ_V;
    float* inputsT  = (float*)p;  p += (size_t)TIN * BATCH * sizeof(float);
    __bf16* h0 = (__bf16*)p;      p += SZ_HF;
    __bf16* h1 = (__bf16*)p;      p += SZ_HF;
    float* xacc  = (float*)p;     p += 3 * BATCH * sizeof(float);
    int* barrier_ws = (int*)p;    p += 1024 * sizeof(int);

    pack_w<<<512, 256, 0, stream>>>(enc_Whh, ApkEnc);
    pack_w<<<512, 256, 0, stream>>>(dec_Whh, ApkDec);
    pack_v<<<8, 256, 0, stream>>>(enc_Wih, enc_b, WihPenc, biasPenc);
    pack_v<<<8, 256, 0, stream>>>(dec_Wih, dec_b, WihPdec, biasPdec);
    transpose_in<<<1024, 256, 0, stream>>>(inputs, inputsT);
    hipMemsetAsync(h0, 0, SZ_HF, stream);
    hipMemsetAsync(xacc, 0, 3 * BATCH * sizeof(float), stream);
    hipMemsetAsync(barrier_ws, 0, 1024 * sizeof(int), stream);

    const int shmem = 131072 + 16384 + 5120 + 128;   // A + ring + hstage(padded) + xred
    hipFuncSetAttribute((const void*)lstm_persistent,
                        hipFuncAttributeMaxDynamicSharedMemorySize, shmem);

    void* args[] = {
        (void*)&ApkEnc, (void*)&ApkDec,
        (void*)&WihPenc, (void*)&biasPenc, (void*)&WihPdec, (void*)&biasPdec,
        (void*)&inputsT, (void*)&lin_W, (void*)&lin_b,
        (void*)&h0, (void*)&h1,
        (void*)&xacc, (void*)&barrier_ws, (void*)&out
    };
    hipLaunchCooperativeKernel((void*)lstm_persistent, dim3(256), dim3(256),
                               args, shmem, stream);
}

// Round 8
// 4141.944 us; speedup vs baseline: 2.2966x; 1.0141x over previous
//
#include <hip/hip_runtime.h>
#include <math.h>

#define HID    512
#define BATCH  512
#define TIN    512
#define TOUT   128
#define FOUR_H 2048
#define STEPS  (TIN + TOUT)

typedef __bf16 bf16x8 __attribute__((ext_vector_type(8)));
typedef float floatx4 __attribute__((ext_vector_type(4)));
typedef int   int4v   __attribute__((ext_vector_type(4)));

// LLC-direct (bypass L1+L2) -- for h exchange (coherence point = Infinity Cache).
// R15 measured: sc0-only (L2) path is ~2x SLOWER per-CU; sc0sc1 is the fast path.
#define GLOADX4_SC(dst, p) \
    asm volatile("global_load_dwordx4 %0, %1, off sc0 sc1" : "=v"(dst) : "v"(p))
#define GSTOREX4_SC(p, v) \
    asm volatile("global_store_dwordx4 %0, %1, off sc0 sc1" :: "v"(p), "v"(v) : "memory")
// normal cached load -- for read-only streamed A (hits XCD L2)
#define GLOADX4_C(dst, p) \
    asm volatile("global_load_dwordx4 %0, %1, off" : "=v"(dst) : "v"(p))
// exact-count waits, tying the consumed registers
#define WAIT_T1(N, r) asm volatile("s_waitcnt vmcnt(" #N ")" : "+v"(r))
#define WAIT_T4(N, B) asm volatile("s_waitcnt vmcnt(" #N ")" \
    : "+v"((B)[0]), "+v"((B)[1]), "+v"((B)[2]), "+v"((B)[3]))

// R17: workgroup barrier that does NOT drain vmcnt. __syncthreads() makes hipcc
// emit "s_waitcnt vmcnt(0) lgkmcnt(0); s_barrier", which forces every in-flight
// global load to complete at each K-loop sync -- serializing the LLC RTTs and
// killing the software pipeline. lgkmcnt(0) alone guarantees the ring ds_writes
// are visible across the barrier; the sc B loads / cached A loads stay in flight
// (AITER pattern: loads cross the barrier; vmcnt waits stay counted).
#define BAR_LDS() asm volatile("s_waitcnt lgkmcnt(0)\n\ts_barrier" ::: "memory")

__device__ __forceinline__ float fsig(float x) {
    return __builtin_amdgcn_rcpf(1.0f + __expf(-x));
}
__device__ __forceinline__ float ftanh(float x) {
    return 1.0f - 2.0f * __builtin_amdgcn_rcpf(1.0f + __expf(2.0f * x));
}

// ---------- prep: pack Whh into blocked MFMA A-fragment order, bf16 hi/lo.
// m' = 4*j+g (row r = g*512+j); blk = m'>>7 (16 blocks x 128 rows),
// rg = (m'>>4)&7 (8 row-groups of 16), lr = m'&15; chunk = k>>5, lq=(k>>3)&3,
// lane = lq*16+lr.  elem-off = ((((blk*8+rg)*16+chunk)*2+pl)*512 + lane*8).
__global__ __launch_bounds__(256) void pack_w(
    const float* __restrict__ W, __bf16* __restrict__ Apk)
{
    int tid = blockIdx.x * 256 + threadIdx.x;   // 131072 threads
    int mp  = tid >> 6;                         // m' in [0,2048)
    int kg  = tid & 63;                         // k-group of 8
    int g   = mp & 3;
    int j   = mp >> 2;
    int r   = g * HID + j;
    int blk   = mp >> 7;
    int rg    = (mp >> 4) & 7;
    int lr    = mp & 15;
    int chunk = kg >> 2;
    int lq    = kg & 3;
    int lane  = lq * 16 + lr;
    const float* src = W + (size_t)r * HID + kg * 8;
    size_t offHi = ((size_t)(((blk * 8 + rg) * 16 + chunk) * 2 + 0) * 512) + lane * 8;
    size_t offLo = ((size_t)(((blk * 8 + rg) * 16 + chunk) * 2 + 1) * 512) + lane * 8;
    __bf16 hibuf[8], lobuf[8];
    #pragma unroll
    for (int i = 0; i < 8; ++i) {
        float x = src[i];
        __bf16 hi = (__bf16)x;
        hibuf[i] = hi;
        lobuf[i] = (__bf16)(x - (float)hi);
    }
    *(bf16x8*)(Apk + offHi) = *(bf16x8*)hibuf;
    *(bf16x8*)(Apk + offLo) = *(bf16x8*)lobuf;
}

__global__ __launch_bounds__(256) void pack_v(
    const float* __restrict__ Wih, const float* __restrict__ b,
    float* __restrict__ WihP, float* __restrict__ bP)
{
    int mp = blockIdx.x * 256 + threadIdx.x;
    int g  = mp & 3;
    int j  = mp >> 2;
    int r  = g * HID + j;
    WihP[mp] = Wih[r];
    bP[mp]   = b[r];
}

__global__ __launch_bounds__(256) void transpose_in(
    const float* __restrict__ in, float* __restrict__ outT)
{
    int idx = blockIdx.x * 256 + threadIdx.x;
    int t = idx >> 9, b = idx & 511;
    outT[idx] = in[(size_t)b * TIN + t];
}

// ---------- persistent cooperative kernel ----------
// grid 256 = 16 blk (128 m') x 16 by (32 b); block 256 = 4 waves; 1 block/CU.
// R16 (4200us): fire-and-forget arrive + it0/A-prefetch in the barrier window.
// R17: K-loop barriers keep vmcnt counted (BAR_LDS) so B/A prefetches genuinely
// stay in flight across iterations; vmcnt tables (R10-derived) unchanged --
// they were derived for exactly this no-drain regime.
__global__ __launch_bounds__(256, 1) void lstm_persistent(
    const __bf16* __restrict__ ApkEnc,   // [16 blk][8 rg][16 ch][2 pl][512], 4 MB
    const __bf16* __restrict__ ApkDec,
    const float* __restrict__ WihPenc, const float* __restrict__ biasPenc,
    const float* __restrict__ WihPdec, const float* __restrict__ biasPdec,
    const float* __restrict__ inputsT,
    const float* __restrict__ linW, const float* __restrict__ linb,
    __bf16* __restrict__ h0,         // [16 by][16 ch][256 piece][8] = 1 MB
    __bf16* __restrict__ h1,
    float* __restrict__ xacc,        // [3][BATCH] rotating decoder-feedback accum
    int* __restrict__ barrier_ws,    // arrive counters [by*32]
    float* __restrict__ out)         // [BATCH][TOUT]
{
    extern __shared__ char smem[];
    __bf16* Alds   = (__bf16*)smem;                    // 131072 B (A rows 0-63 hi/lo)
    char*   Bring  = smem + 131072;                    // 4 slots x 4096 B
    __bf16* hstage = (__bf16*)(smem + 147456);         // [64 rows][40] bf16 = 5120 B
    float*  xred   = (float*)(smem + 152576);          // [32]

    const int tid  = threadIdx.x;
    const int lane = tid & 63;
    const int w    = tid >> 6;
    const int lr   = lane & 15;
    const int lq   = lane >> 4;
    const int by   = blockIdx.x >> 4;       // 16 batch groups
    const int blk  = blockIdx.x & 15;       // 16 m' blocks
    const int nbase = by * 32;
    const int rgbase = 2 * w;               // wave w owns row-groups {2w, 2w+1}
    const bool STREAM = (w >= 2);           // rg 4..7 streamed from L2

    int* arrive = barrier_ws + by * 32;

    // lane's packed-m' base for (mb): blk*128 + (rgbase+mb)*16 + lq*4
    const int m0a = blk * 128 + (rgbase + 0) * 16 + lq * 4;
    const int m0b = blk * 128 + (rgbase + 1) * 16 + lq * 4;
    const floatx4 wihE[2] = { *(const floatx4*)(WihPenc + m0a), *(const floatx4*)(WihPenc + m0b) };
    const floatx4 bE[2]   = { *(const floatx4*)(biasPenc + m0a), *(const floatx4*)(biasPenc + m0b) };
    const floatx4 wihD[2] = { *(const floatx4*)(WihPdec + m0a), *(const floatx4*)(WihPdec + m0b) };
    const floatx4 bD[2]   = { *(const floatx4*)(biasPdec + m0a), *(const floatx4*)(biasPdec + m0b) };
    const float lw[2] = { linW[m0a >> 2], linW[m0b >> 2] };   // j = m'>>2
    const float lb = linb[0];

    int bn[2];
    #pragma unroll
    for (int nt = 0; nt < 2; ++nt) bn[nt] = nbase + nt * 16 + lr;

    // zero hstage (step 0's it0 reads own chunk of h(-1)=0 from it)
    {
        float* hz = (float*)hstage;
        for (int i = tid; i < 1280; i += 256) hz[i] = 0.f;
    }
    // stage resident A half (rg 0..3): linear 128 KB copy
    {
        const int4v* srcp = (const int4v*)(ApkEnc + (size_t)blk * 131072);
        int4v* dstp = (int4v*)Alds;
        for (int i = tid; i < 8192; i += 256) dstp[i] = srcp[i];
    }
    __syncthreads();
    __builtin_amdgcn_s_waitcnt(0);   // clean vmcnt state before scheduled issues

    float creg[2][2] = {{0.f, 0.f}, {0.f, 0.f}};

    floatx4 acc[2][2];
    int4v areg[2][4];

    // ---- pre-segment for step 0: A0/A1 prefetch + it0 (hstage = 0 -> acc = 0) ----
    {
        const __bf16* AgN = ApkEnc + (size_t)blk * 131072;
        #pragma unroll
        for (int mb = 0; mb < 2; ++mb)
            #pragma unroll
            for (int nt = 0; nt < 2; ++nt) acc[mb][nt] = floatx4{0.f, 0.f, 0.f, 0.f};
        if (STREAM) {
            #pragma unroll
            for (int mb = 0; mb < 2; ++mb)
                #pragma unroll
                for (int pl = 0; pl < 2; ++pl)
                    GLOADX4_C(areg[0][mb * 2 + pl],
                              AgN + (size_t)((((rgbase + mb) * 16 + blk) * 2 + pl) * 512) + lane * 8);
            #pragma unroll
            for (int mb = 0; mb < 2; ++mb)
                #pragma unroll
                for (int pl = 0; pl < 2; ++pl)
                    GLOADX4_C(areg[1][mb * 2 + pl],
                              AgN + (size_t)((((rgbase + mb) * 16 + ((blk + 1) & 15)) * 2 + pl) * 512) + lane * 8);
            WAIT_T4(4, areg[0]);
        }
        // it0 for step 0
        bf16x8 ah[2], al[2];
        if (STREAM) {
            #pragma unroll
            for (int mb = 0; mb < 2; ++mb) {
                ah[mb] = __builtin_bit_cast(bf16x8, areg[0][mb * 2 + 0]);
                al[mb] = __builtin_bit_cast(bf16x8, areg[0][mb * 2 + 1]);
            }
        } else {
            #pragma unroll
            for (int mb = 0; mb < 2; ++mb) {
                const char* ap = (const char*)Alds + (((rgbase + mb) * 16 + blk) * 2) * 1024 + lane * 16;
                ah[mb] = *(const bf16x8*)(ap);
                al[mb] = *(const bf16x8*)(ap + 1024);
            }
        }
        const char* hb = (const char*)hstage;
        const int kq = lane >> 4, lrp = lane & 15;
        bf16x8 bh0 = *(const bf16x8*)(hb + (     lrp) * 80 + kq * 16);
        bf16x8 bl0 = *(const bf16x8*)(hb + (32 + lrp) * 80 + kq * 16);
        bf16x8 bh1 = *(const bf16x8*)(hb + (16 + lrp) * 80 + kq * 16);
        bf16x8 bl1 = *(const bf16x8*)(hb + (48 + lrp) * 80 + kq * 16);
        #pragma unroll
        for (int mb = 0; mb < 2; ++mb) {
            acc[mb][0] = __builtin_amdgcn_mfma_f32_16x16x32_bf16(ah[mb], bh0, acc[mb][0], 0, 0, 0);
            acc[mb][1] = __builtin_amdgcn_mfma_f32_16x16x32_bf16(ah[mb], bh1, acc[mb][1], 0, 0, 0);
            acc[mb][0] = __builtin_amdgcn_mfma_f32_16x16x32_bf16(al[mb], bh0, acc[mb][0], 0, 0, 0);
            acc[mb][1] = __builtin_amdgcn_mfma_f32_16x16x32_bf16(al[mb], bh1, acc[mb][1], 0, 0, 0);
            acc[mb][0] = __builtin_amdgcn_mfma_f32_16x16x32_bf16(ah[mb], bl0, acc[mb][0], 0, 0, 0);
            acc[mb][1] = __builtin_amdgcn_mfma_f32_16x16x32_bf16(ah[mb], bl1, acc[mb][1], 0, 0, 0);
        }
    }

    for (int s = 0; s < STEPS; ++s) {
        const bool dec = (s >= TIN);
        const int  t   = s - TIN;
        const __bf16* Acur = dec ? ApkDec : ApkEnc;

        const __bf16* hin  = (s & 1) ? h1 : h0;
        __bf16*       hout = (s & 1) ? h0 : h1;
        const __bf16* srcB = hin + (size_t)by * 32768 + tid * 8;    // + chunk*2048
        const __bf16* Ag   = Acur + (size_t)blk * 131072;

        // ---- bookkeeping first (oldest vmem, drained by it1's wait) ----
        float xq[2];
        if (dec) {
            if (tid < 32) xred[tid] = 0.f;
            if (blk == 0) {
                if (t >= 1 && tid < 32) {
                    float v = __hip_atomic_load(&xacc[((t - 1) % 3) * BATCH + nbase + tid],
                                                __ATOMIC_RELAXED, __HIP_MEMORY_SCOPE_AGENT) + lb;
                    out[(size_t)(nbase + tid) * TOUT + (t - 1)] = v;
                }
                if (tid >= 32 && tid < 64) {
                    __hip_atomic_store(&xacc[((t + 1) % 3) * BATCH + nbase + (tid - 32)], 0.0f,
                                       __ATOMIC_RELAXED, __HIP_MEMORY_SCOPE_AGENT);
                }
            }
            #pragma unroll
            for (int nt = 0; nt < 2; ++nt)
                xq[nt] = (t == 0) ? inputsT[(TIN - 1) * BATCH + bn[nt]]
                                  : __hip_atomic_load(&xacc[((t - 1) % 3) * BATCH + bn[nt]],
                                                      __ATOMIC_RELAXED, __HIP_MEMORY_SCOPE_AGENT) + lb;
        } else {
            #pragma unroll
            for (int nt = 0; nt < 2; ++nt)
                xq[nt] = inputsT[s * BATCH + bn[nt]];
        }
        asm volatile("" ::: "memory");   // pin bookkeeping vmem above staging asm

        // ---- B prologue: chunks blk+1, blk+2, blk+3 (it0 already done pre-barrier) ----
        int4v st[4];
        GLOADX4_SC(st[1], srcB + (size_t)((blk + 1) & 15) * 2048);
        GLOADX4_SC(st[2], srcB + (size_t)((blk + 2) & 15) * 2048);
        GLOADX4_SC(st[3], srcB + (size_t)((blk + 3) & 15) * 2048);

        // ---- K-loop it=1..15. STREAM age order:
        // [A1(pre-seg) | bk | B1,B2,B3 | it1:(A2,B4) it2:(A3,B5) ... it12:(A13,B15)
        //  it13:(A14) it14:(A15)]
        // (a): it1=2 (forces A1,bk,B1), it2=6, it3..15 none (prior (d) retired B(it)).
        // (d): it1 none (A1 retired at it1(a)), it2-12=6, it13=5, it14=4, it15=0.
        // non-STREAM (a): <=13 -> 2, 14 -> 1, 15 -> 0 (R10 table).
        #pragma unroll
        for (int it = 1; it < 16; ++it) {
            const int c = (blk + it) & 15;

            // (a) wait B(it) resident, write ring slot
            if (STREAM) {
                if      (it == 1) { WAIT_T1(2, st[1]); }
                else if (it == 2) { WAIT_T1(6, st[2]); }
                // it >= 3: B(it) already forced by it-1's (d) wait
            } else {
                if      (it <= 13) { WAIT_T1(2, st[it & 3]); }
                else if (it == 14) { WAIT_T1(1, st[it & 3]); }
                else               { WAIT_T1(0, st[it & 3]); }
            }
            *(int4v*)(Bring + (it & 3) * 4096 + tid * 16) = st[it & 3];

            // (b') issue A(it+1) then B(it+3)
            if (STREAM && it + 1 < 16) {
                const int cn = (blk + it + 1) & 15;
                #pragma unroll
                for (int mb = 0; mb < 2; ++mb)
                    #pragma unroll
                    for (int pl = 0; pl < 2; ++pl)
                        GLOADX4_C(areg[(it + 1) & 1][mb * 2 + pl],
                                  Ag + (size_t)((((rgbase + mb) * 16 + cn) * 2 + pl) * 512) + lane * 8);
            }
            if (it + 3 < 16)
                GLOADX4_SC(st[(it + 3) & 3], srcB + (size_t)((blk + it + 3) & 15) * 2048);

            BAR_LDS();   // chunk `it` visible in ring; vmcnt stays counted (R17)

            // (d) A fragments
            bf16x8 ah[2], al[2];
            if (STREAM) {
                if      (it == 1)  { /* A1 retired at (a) */ }
                else if (it <= 12) { WAIT_T4(6, areg[it & 1]); }
                else if (it == 13) { WAIT_T4(5, areg[1]); }
                else if (it == 14) { WAIT_T4(4, areg[0]); }
                else               { WAIT_T4(0, areg[1]); }
                #pragma unroll
                for (int mb = 0; mb < 2; ++mb) {
                    ah[mb] = __builtin_bit_cast(bf16x8, areg[it & 1][mb * 2 + 0]);
                    al[mb] = __builtin_bit_cast(bf16x8, areg[it & 1][mb * 2 + 1]);
                }
            } else {
                #pragma unroll
                for (int mb = 0; mb < 2; ++mb) {
                    const char* ap = (const char*)Alds
                        + (((rgbase + mb) * 16 + c) * 2) * 1024 + lane * 16;
                    ah[mb] = *(const bf16x8*)(ap);
                    al[mb] = *(const bf16x8*)(ap + 1024);
                }
            }

            const char* bs = Bring + (it & 3) * 4096;
            bf16x8 bh0 = *(const bf16x8*)(bs + (0 * 128 + 0 * 64 + lane) * 16);
            bf16x8 bl0 = *(const bf16x8*)(bs + (0 * 128 + 1 * 64 + lane) * 16);
            bf16x8 bh1 = *(const bf16x8*)(bs + (1 * 128 + 0 * 64 + lane) * 16);
            bf16x8 bl1 = *(const bf16x8*)(bs + (1 * 128 + 1 * 64 + lane) * 16);

            #pragma unroll
            for (int mb = 0; mb < 2; ++mb) {
                acc[mb][0] = __builtin_amdgcn_mfma_f32_16x16x32_bf16(ah[mb], bh0, acc[mb][0], 0, 0, 0);
                acc[mb][1] = __builtin_amdgcn_mfma_f32_16x16x32_bf16(ah[mb], bh1, acc[mb][1], 0, 0, 0);
                acc[mb][0] = __builtin_amdgcn_mfma_f32_16x16x32_bf16(al[mb], bh0, acc[mb][0], 0, 0, 0);
                acc[mb][1] = __builtin_amdgcn_mfma_f32_16x16x32_bf16(al[mb], bh1, acc[mb][1], 0, 0, 0);
                acc[mb][0] = __builtin_amdgcn_mfma_f32_16x16x32_bf16(ah[mb], bl0, acc[mb][0], 0, 0, 0);
                acc[mb][1] = __builtin_amdgcn_mfma_f32_16x16x32_bf16(ah[mb], bl1, acc[mb][1], 0, 0, 0);
            }
        }

        // ---- epilogue: gates, c in regs, stage h tile to LDS (40-elem rows) ----
        const floatx4* wih = dec ? wihD : wihE;
        const floatx4* bb  = dec ? bD   : bE;
        float px[2] = {0.f, 0.f};
        #pragma unroll
        for (int mb = 0; mb < 2; ++mb) {
            const int jlocal = (rgbase + mb) * 4 + lq;   // 0..31
            #pragma unroll
            for (int nt = 0; nt < 2; ++nt) {
                float x  = xq[nt];
                float i_ = fsig (acc[mb][nt][0] + bb[mb][0] + x * wih[mb][0]);
                float f_ = fsig (acc[mb][nt][1] + bb[mb][1] + x * wih[mb][1]);
                float g_ = ftanh(acc[mb][nt][2] + bb[mb][2] + x * wih[mb][2]);
                float o_ = fsig (acc[mb][nt][3] + bb[mb][3] + x * wih[mb][3]);
                float cv = f_ * creg[mb][nt] + i_ * g_;
                creg[mb][nt] = cv;
                float h  = o_ * ftanh(cv);
                __bf16 hh = (__bf16)h;
                int bl = nt * 16 + lr;
                hstage[bl * 40 + jlocal] = hh;                              // pl 0
                hstage[(32 + bl) * 40 + jlocal] = (__bf16)(h - (float)hh);  // pl 1
                if (dec) {
                    float v = h * lw[mb];
                    px[nt] += v;
                }
            }
        }
        if (dec) {
            #pragma unroll
            for (int nt = 0; nt < 2; ++nt) {
                px[nt] += __shfl_xor(px[nt], 16);
                px[nt] += __shfl_xor(px[nt], 32);   // sum over lq
            }
        }

        __syncthreads();   // hstage complete; xred zero visible (vmcnt=0 here anyway)

        // producer h store: thread tid -> piece tid of chunk `blk` (coalesced sc1)
        {
            int nt = tid >> 7, pl = (tid >> 6) & 1, ln = tid & 63;
            int kq = ln >> 4, lrp = ln & 15;
            const char* src = (const char*)hstage + (pl * 32 + nt * 16 + lrp) * 80 + kq * 16;
            int4v v = *(const int4v*)src;
            __bf16* dst = hout + (size_t)by * 32768 + blk * 2048 + tid * 8;
            GSTOREX4_SC(dst, v);
        }

        if (dec && lane < 16) {
            #pragma unroll
            for (int nt = 0; nt < 2; ++nt) atomicAdd(&xred[nt * 16 + lr], px[nt]);
        }
        BAR_LDS();   // xred visible; h-store stays in flight until explicit drain
        if (dec && tid < 32) {
            atomicAdd(&xacc[(t % 3) * BATCH + nbase + tid], xred[tid]);
        }

        // ---- publish: drain (release; own sc reads retired), FIRE arrive ----
        __builtin_amdgcn_s_waitcnt(0);   // h stores + xacc atomics at LLC
        __syncthreads();
        if (tid == 0) {
            (void)__hip_atomic_fetch_add(arrive, 1, __ATOMIC_RELAXED, __HIP_MEMORY_SCOPE_AGENT);
        }

        // ---- overlap window: restage / A-prefetch / it0(s+1) during barrier wait ----
        if (s + 1 == TIN) {
            const int4v* srcp = (const int4v*)(ApkDec + (size_t)blk * 131072);
            int4v* dstp = (int4v*)Alds;
            for (int i = tid; i < 8192; i += 256) dstp[i] = srcp[i];
            __syncthreads();
            __builtin_amdgcn_s_waitcnt(0);   // clean vmcnt before scheduled A issues
        }
        if (s + 1 < STEPS) {
            const __bf16* AgN = ((s + 1 >= TIN) ? ApkDec : ApkEnc) + (size_t)blk * 131072;
            #pragma unroll
            for (int mb = 0; mb < 2; ++mb)
                #pragma unroll
                for (int nt = 0; nt < 2; ++nt) acc[mb][nt] = floatx4{0.f, 0.f, 0.f, 0.f};
            if (STREAM) {
                #pragma unroll
                for (int mb = 0; mb < 2; ++mb)
                    #pragma unroll
                    for (int pl = 0; pl < 2; ++pl)
                        GLOADX4_C(areg[0][mb * 2 + pl],
                                  AgN + (size_t)((((rgbase + mb) * 16 + blk) * 2 + pl) * 512) + lane * 8);
                #pragma unroll
                for (int mb = 0; mb < 2; ++mb)
                    #pragma unroll
                    for (int pl = 0; pl < 2; ++pl)
                        GLOADX4_C(areg[1][mb * 2 + pl],
                                  AgN + (size_t)((((rgbase + mb) * 16 + ((blk + 1) & 15)) * 2 + pl) * 512) + lane * 8);
                WAIT_T4(4, areg[0]);
            }
            // it0 for step s+1: B from hstage (own tile), A chunk blk
            bf16x8 ah[2], al[2];
            if (STREAM) {
                #pragma unroll
                for (int mb = 0; mb < 2; ++mb) {
                    ah[mb] = __builtin_bit_cast(bf16x8, areg[0][mb * 2 + 0]);
                    al[mb] = __builtin_bit_cast(bf16x8, areg[0][mb * 2 + 1]);
                }
            } else {
                #pragma unroll
                for (int mb = 0; mb < 2; ++mb) {
                    const char* ap = (const char*)Alds + (((rgbase + mb) * 16 + blk) * 2) * 1024 + lane * 16;
                    ah[mb] = *(const bf16x8*)(ap);
                    al[mb] = *(const bf16x8*)(ap + 1024);
                }
            }
            const char* hb = (const char*)hstage;
            const int kq = lane >> 4, lrp = lane & 15;
            bf16x8 bh0 = *(const bf16x8*)(hb + (     lrp) * 80 + kq * 16);
            bf16x8 bl0 = *(const bf16x8*)(hb + (32 + lrp) * 80 + kq * 16);
            bf16x8 bh1 = *(const bf16x8*)(hb + (16 + lrp) * 80 + kq * 16);
            bf16x8 bl1 = *(const bf16x8*)(hb + (48 + lrp) * 80 + kq * 16);
            #pragma unroll
            for (int mb = 0; mb < 2; ++mb) {
                acc[mb][0] = __builtin_amdgcn_mfma_f32_16x16x32_bf16(ah[mb], bh0, acc[mb][0], 0, 0, 0);
                acc[mb][1] = __builtin_amdgcn_mfma_f32_16x16x32_bf16(ah[mb], bh1, acc[mb][1], 0, 0, 0);
                acc[mb][0] = __builtin_amdgcn_mfma_f32_16x16x32_bf16(al[mb], bh0, acc[mb][0], 0, 0, 0);
                acc[mb][1] = __builtin_amdgcn_mfma_f32_16x16x32_bf16(al[mb], bh1, acc[mb][1], 0, 0, 0);
                acc[mb][0] = __builtin_amdgcn_mfma_f32_16x16x32_bf16(ah[mb], bl0, acc[mb][0], 0, 0, 0);
                acc[mb][1] = __builtin_amdgcn_mfma_f32_16x16x32_bf16(ah[mb], bl1, acc[mb][1], 0, 0, 0);
            }
        }

        // ---- gate: poll count (first poll typically lands after all 16 adds) ----
        if (tid == 0) {
            int target = 16 * (s + 1);
            int n;
            do {
                n = __hip_atomic_load(arrive, __ATOMIC_RELAXED, __HIP_MEMORY_SCOPE_AGENT);
                if (n >= target) break;
                __builtin_amdgcn_s_sleep(2);
            } while (1);
        }
        __syncthreads();
    }

    // tail: out[:, TOUT-1]  (last poll guaranteed all blocks' final xacc drained)
    if (blk == 0 && tid < 32) {
        float v = __hip_atomic_load(&xacc[((TOUT - 1) % 3) * BATCH + nbase + tid],
                                    __ATOMIC_RELAXED, __HIP_MEMORY_SCOPE_AGENT) + lb;
        out[(size_t)(nbase + tid) * TOUT + (TOUT - 1)] = v;
    }
}

extern "C" void kernel_launch(void* const* d_in, const int* in_sizes, int n_in,
                              void* d_out, int out_size, void* d_ws, size_t ws_size,
                              hipStream_t stream) {
    const float* inputs  = (const float*)d_in[0];
    const float* enc_Wih = (const float*)d_in[2];
    const float* enc_Whh = (const float*)d_in[3];
    const float* enc_b   = (const float*)d_in[4];
    const float* dec_Wih = (const float*)d_in[5];
    const float* dec_Whh = (const float*)d_in[6];
    const float* dec_b   = (const float*)d_in[7];
    const float* lin_W   = (const float*)d_in[8];
    const float* lin_b   = (const float*)d_in[9];
    float* out = (float*)d_out;

    char* ws = (char*)d_ws;
    const size_t SZ_APK = (size_t)FOUR_H * HID * 2 * sizeof(__bf16);   // 4 MB
    const size_t SZ_V   = (size_t)FOUR_H * sizeof(float);
    const size_t SZ_HF  = (size_t)16 * 16 * 256 * 8 * sizeof(__bf16);  // 1 MB

    __bf16* ApkEnc = (__bf16*)(ws);
    __bf16* ApkDec = (__bf16*)(ws + SZ_APK);
    char* p = ws + 2 * SZ_APK;
    float* WihPenc  = (float*)p;  p += SZ_V;
    float* biasPenc = (float*)p;  p += SZ_V;
    float* WihPdec  = (float*)p;  p += SZ_V;
    float* biasPdec = (float*)p;  p += SZ_V;
    float* inputsT  = (float*)p;  p += (size_t)TIN * BATCH * sizeof(float);
    __bf16* h0 = (__bf16*)p;      p += SZ_HF;
    __bf16* h1 = (__bf16*)p;      p += SZ_HF;
    float* xacc  = (float*)p;     p += 3 * BATCH * sizeof(float);
    int* barrier_ws = (int*)p;    p += 1024 * sizeof(int);

    pack_w<<<512, 256, 0, stream>>>(enc_Whh, ApkEnc);
    pack_w<<<512, 256, 0, stream>>>(dec_Whh, ApkDec);
    pack_v<<<8, 256, 0, stream>>>(enc_Wih, enc_b, WihPenc, biasPenc);
    pack_v<<<8, 256, 0, stream>>>(dec_Wih, dec_b, WihPdec, biasPdec);
    transpose_in<<<1024, 256, 0, stream>>>(inputs, inputsT);
    hipMemsetAsync(h0, 0, SZ_HF, stream);
    hipMemsetAsync(xacc, 0, 3 * BATCH * sizeof(float), stream);
    hipMemsetAsync(barrier_ws, 0, 1024 * sizeof(int), stream);

    const int shmem = 131072 + 16384 + 5120 + 128;   // A + ring + hstage(padded) + xred
    hipFuncSetAttribute((const void*)lstm_persistent,
                        hipFuncAttributeMaxDynamicSharedMemorySize, shmem);

    void* args[] = {
        (void*)&ApkEnc, (void*)&ApkDec,
        (void*)&WihPenc, (void*)&biasPenc, (void*)&WihPdec, (void*)&biasPdec,
        (void*)&inputsT, (void*)&lin_W, (void*)&lin_b,
        (void*)&h0, (void*)&h1,
        (void*)&xacc, (void*)&barrier_ws, (void*)&out
    };
    hipLaunchCooperativeKernel((void*)lstm_persistent, dim3(256), dim3(256),
                               args, shmem, stream);
}